// Round 5
// baseline (16814.133 us; speedup 1.0000x reference)
//
#include <hip/hip_runtime.h>
#include <math.h>

// ---------------------------------------------------------------------------
// SimpleRNN (2-layer LSTM, H=1024, T=4096 sequential steps, batch=1 effective)
//
//   k_clear    : zero the packet buffers (tags must start invalid)
//   k_prep     : gather x (step-major), combine biases
//   gemm_nt    : C[M,N] = A[M,K] @ B[N,K]^T + bias
//   lstm_fused : ONE persistent 256-block kernel, both layer chains, layer-1
//                pipelined one step behind layer-0 (4097 round slots).
//                SYNC = DATA: h travels as 8-byte packets {float h, int tag}
//                via relaxed agent-scope 64-bit stores (one MALL trip/step).
//                This round: weights in VGPRs (no LDS weight re-read),
//                wave u owns ALL 4 gates of unit u -> lane 0 finishes the
//                unit locally (no scr stage, ONE barrier per round).
// ---------------------------------------------------------------------------

#define T_STEPS 4096
#define HID 1024
#define UPB 8            // hidden units per block (= waves per block)
#define NBLK 256         // persistent blocks (128 per layer)
#define THR 512          // threads per recurrence block

typedef unsigned long long u64;

#define AGENT_LD64(p) __hip_atomic_load((p), __ATOMIC_RELAXED, __HIP_MEMORY_SCOPE_AGENT)
#define AGENT_ST64(p, v) __hip_atomic_store((p), (v), __ATOMIC_RELAXED, __HIP_MEMORY_SCOPE_AGENT)

__device__ __forceinline__ u64 pack_h(float h, int tag) {
  return (u64)__float_as_uint(h) | ((u64)(unsigned)tag << 32);
}
__device__ __forceinline__ float pkt_val(u64 v) { return __uint_as_float((unsigned)v); }
__device__ __forceinline__ int pkt_tag(u64 v) { return (int)(v >> 32); }

__global__ void k_clear(u64* __restrict__ p, long n) {
  long i = (long)blockIdx.x * blockDim.x + threadIdx.x;
  long stride = (long)gridDim.x * blockDim.x;
  for (; i < n; i += stride) p[i] = 0ULL;
}

__global__ void k_prep(const float* __restrict__ inputs,
                       const float* __restrict__ b_ih0, const float* __restrict__ b_hh0,
                       const float* __restrict__ b_ih1, const float* __restrict__ b_hh1,
                       float* __restrict__ xg, float* __restrict__ bsum0,
                       float* __restrict__ b1sum) {
  int i = blockIdx.x * 256 + threadIdx.x;   // grid covers 262144
  if (i < T_STEPS * 64) {
    int t = i >> 6, d = i & 63;
    // x[t] = inputs[sample = t%32, step = t/32, :]
    xg[i] = inputs[(t & 31) * 8192 + (t >> 5) * 64 + d];
  }
  if (i < 4096) {
    bsum0[i] = b_ih0[i] + b_hh0[i];
    b1sum[i] = b_ih1[i] + b_hh1[i];
  }
}

// C = A @ B^T + bias.  A: M x K, B: N x K (both row-major, K contiguous).
// 128x128 tile, BK=8, 256 threads, 8x8 micro-tile per thread.
__global__ __launch_bounds__(256) void gemm_nt(
    const float* __restrict__ A, const float* __restrict__ B,
    const float* __restrict__ bias, float* __restrict__ C,
    int M, int N, int K, int mode) {
  __shared__ float As[8][128];
  __shared__ float Bs[8][128];
  const int tid = threadIdx.x;
  const int bm = blockIdx.x * 128;
  const int bn = blockIdx.y * 128;
  const int tm = tid >> 4;
  const int tn = tid & 15;
  const int lr = tid >> 1;
  const int lk = (tid & 1) * 4;

  float acc[8][8];
#pragma unroll
  for (int i = 0; i < 8; i++)
#pragma unroll
    for (int j = 0; j < 8; j++) acc[i][j] = 0.f;

  const float* Ap = A + (long)(bm + lr) * K + lk;
  const bool bvalid = (bn + lr) < N;
  const float* Bp = B + (long)(bvalid ? (bn + lr) : 0) * K + lk;

  for (int k0 = 0; k0 < K; k0 += 8) {
    float4 av = *(const float4*)(Ap + k0);
    float4 bv = bvalid ? *(const float4*)(Bp + k0) : make_float4(0.f, 0.f, 0.f, 0.f);
    As[lk + 0][lr] = av.x; As[lk + 1][lr] = av.y;
    As[lk + 2][lr] = av.z; As[lk + 3][lr] = av.w;
    Bs[lk + 0][lr] = bv.x; Bs[lk + 1][lr] = bv.y;
    Bs[lk + 2][lr] = bv.z; Bs[lk + 3][lr] = bv.w;
    __syncthreads();
#pragma unroll
    for (int kk = 0; kk < 8; kk++) {
      float a[8], b[8];
      *(float4*)&a[0] = *(const float4*)&As[kk][tm * 8];
      *(float4*)&a[4] = *(const float4*)&As[kk][tm * 8 + 4];
      *(float4*)&b[0] = *(const float4*)&Bs[kk][tn * 8];
      *(float4*)&b[4] = *(const float4*)&Bs[kk][tn * 8 + 4];
#pragma unroll
      for (int i = 0; i < 8; i++)
#pragma unroll
        for (int j = 0; j < 8; j++) acc[i][j] = fmaf(a[i], b[j], acc[i][j]);
    }
    __syncthreads();
  }

  const int n0 = bn + tn * 8;
  if (n0 < N) {
    float bb[8];
#pragma unroll
    for (int j = 0; j < 8; j++) bb[j] = bias[n0 + j];
#pragma unroll
    for (int i = 0; i < 8; i++) {
      int m = bm + tm * 8 + i;
      float4 v0, v1;
      v0.x = acc[i][0] + bb[0]; v0.y = acc[i][1] + bb[1];
      v0.z = acc[i][2] + bb[2]; v0.w = acc[i][3] + bb[3];
      v1.x = acc[i][4] + bb[4]; v1.y = acc[i][5] + bb[5];
      v1.z = acc[i][6] + bb[6]; v1.w = acc[i][7] + bb[7];
      if (mode == 0) {
        long o = (long)m * N + n0;
        *(float4*)&C[o] = v0; *(float4*)&C[o + 4] = v1;
      } else {
        long o = (long)(m & 31) * 8192 + (long)(m >> 5) * 64 + n0;
        *(float4*)&C[o] = v0; *(float4*)&C[o + 4] = v1;
      }
    }
  }
}

__device__ __forceinline__ float sigmf(float x) { return 1.f / (1.f + expf(-x)); }

// Fused 2-layer recurrence. 256 blocks x 512 threads, 1 block/CU (LDS-padded).
// Wave u owns unit j0+u's 4 gate rows; lane l covers k in [16l, 16l+16).
__global__ __launch_bounds__(THR, 2) void lstm_fused(
    const float* __restrict__ pre0,   // T x 4096 (layer-0 biases included)
    const float* __restrict__ Whh0,   // 4096 x 1024
    const float* __restrict__ Wih1,   // 4096 x 1024
    const float* __restrict__ Whh1,   // 4096 x 1024
    const float* __restrict__ b1sum,  // 4096
    u64* __restrict__ pk0,            // T x 1024 packets {h0, tag=t+1}
    u64* __restrict__ pk1,            // T x 1024 packets {h1, tag=t+1}
    float* __restrict__ h1_hist) {    // T x 1024 plain (for output GEMM)
  __shared__ float ha_lds[HID];       // 4 KB
  __shared__ float hb_lds[HID];       // 4 KB (layer-1 only)
  __shared__ float pad_lds[18432];    // 72 KB: forces 1 block/CU
  const int b = blockIdx.x;
  const int tid = threadIdx.x;
  const int wave = tid >> 6;          // = unit index u within the block
  const int lane = tid & 63;
  const int koff = lane * 16;

  // never true at runtime; keeps pad_lds alive (arg value unknown to compiler)
  if (pre0 == nullptr) { pad_lds[tid] = (float)tid; ha_lds[0] = pad_lds[tid ^ 1]; }

  if (b < 128) {
    // ----------------------------- layer 0 -------------------------------
    const int j0 = b * UPB;
    const int unit = j0 + wave;
    float w[4][16];                   // W_hh0 rows for this unit's 4 gates
#pragma unroll
    for (int g = 0; g < 4; g++) {
      const float* src = Whh0 + (long)(g * HID + unit) * HID + koff;
#pragma unroll
      for (int q = 0; q < 4; q++)
        *(float4*)&w[g][q * 4] = *(const float4*)(src + q * 4);
    }
    float c_state = 0.f;              // valid in lane 0

    for (int t = 0; t < T_STEPS; t++) {
      float pv[4] = {0.f, 0.f, 0.f, 0.f};   // prefetch overlaps the poll
      if (lane == 0) {
#pragma unroll
        for (int g = 0; g < 4; g++)
          pv[g] = pre0[(long)t * 4096 + g * HID + unit];
      }

      if (t > 0) {
        const u64* p = pk0 + (long)(t - 1) * HID + 2 * tid;
        u64 va, vb;
        for (;;) {
          va = AGENT_LD64(p);
          vb = AGENT_LD64(p + 1);
          if (pkt_tag(va) == t && pkt_tag(vb) == t) break;
          __builtin_amdgcn_s_sleep(1);
        }
        ha_lds[2 * tid]     = pkt_val(va);
        ha_lds[2 * tid + 1] = pkt_val(vb);
      } else {
        ha_lds[2 * tid] = 0.f; ha_lds[2 * tid + 1] = 0.f;
      }
      __syncthreads();

      float hf[16];
#pragma unroll
      for (int q = 0; q < 4; q++)
        *(float4*)&hf[q * 4] = *(const float4*)&ha_lds[koff + q * 4];
      float s[4] = {0.f, 0.f, 0.f, 0.f};
#pragma unroll
      for (int j = 0; j < 16; j++) {
#pragma unroll
        for (int g = 0; g < 4; g++) s[g] = fmaf(w[g][j], hf[j], s[g]);
      }
#pragma unroll
      for (int off = 32; off >= 1; off >>= 1) {
#pragma unroll
        for (int g = 0; g < 4; g++) s[g] += __shfl_xor(s[g], off, 64);
      }
      if (lane == 0) {
        float gi = s[0] + pv[0], gf = s[1] + pv[1];
        float gg = s[2] + pv[2], go = s[3] + pv[3];
        c_state = sigmf(gf) * c_state + sigmf(gi) * tanhf(gg);
        float h = sigmf(go) * tanhf(c_state);
        AGENT_ST64(&pk0[(long)t * HID + unit], pack_h(h, t + 1));
      }
      // single barrier per round: LDS reuse is gated by the packet chain
    }
  } else {
    // ----------------------------- layer 1 -------------------------------
    const int j0 = (b - 128) * UPB;
    const int unit = j0 + wave;
    float wih[4][16], whh[4][16];
#pragma unroll
    for (int g = 0; g < 4; g++) {
      const float* s0 = Wih1 + (long)(g * HID + unit) * HID + koff;
      const float* s1 = Whh1 + (long)(g * HID + unit) * HID + koff;
#pragma unroll
      for (int q = 0; q < 4; q++) {
        *(float4*)&wih[g][q * 4] = *(const float4*)(s0 + q * 4);
        *(float4*)&whh[g][q * 4] = *(const float4*)(s1 + q * 4);
      }
    }
    float bs[4] = {0.f, 0.f, 0.f, 0.f};
    if (lane == 0) {
#pragma unroll
      for (int g = 0; g < 4; g++) bs[g] = b1sum[g * HID + unit];
    }
    float c_state = 0.f;              // valid in lane 0

    for (int r = 1; r <= T_STEPS; r++) {   // computes h1[r-1]
      const u64* p0 = pk0 + (long)(r - 1) * HID + 2 * tid;
      const u64* p1 = pk1 + (long)((r >= 2) ? (r - 2) : 0) * HID + 2 * tid;
      u64 a0 = 0, a1 = 0, b0 = 0, b1 = 0;
      bool oka = false, okb = (r < 2);
      for (;;) {
        if (!oka) {
          a0 = AGENT_LD64(p0); a1 = AGENT_LD64(p0 + 1);
          oka = (pkt_tag(a0) == r && pkt_tag(a1) == r);
        }
        if (!okb) {
          b0 = AGENT_LD64(p1); b1 = AGENT_LD64(p1 + 1);
          okb = (pkt_tag(b0) == r - 1 && pkt_tag(b1) == r - 1);
        }
        if (oka && okb) break;
        __builtin_amdgcn_s_sleep(1);
      }
      ha_lds[2 * tid]     = pkt_val(a0);
      ha_lds[2 * tid + 1] = pkt_val(a1);
      hb_lds[2 * tid]     = (r >= 2) ? pkt_val(b0) : 0.f;
      hb_lds[2 * tid + 1] = (r >= 2) ? pkt_val(b1) : 0.f;
      __syncthreads();

      float s[4] = {0.f, 0.f, 0.f, 0.f};
      {
        float hf[16];
#pragma unroll
        for (int q = 0; q < 4; q++)
          *(float4*)&hf[q * 4] = *(const float4*)&ha_lds[koff + q * 4];
#pragma unroll
        for (int j = 0; j < 16; j++) {
#pragma unroll
          for (int g = 0; g < 4; g++) s[g] = fmaf(wih[g][j], hf[j], s[g]);
        }
#pragma unroll
        for (int q = 0; q < 4; q++)
          *(float4*)&hf[q * 4] = *(const float4*)&hb_lds[koff + q * 4];
#pragma unroll
        for (int j = 0; j < 16; j++) {
#pragma unroll
          for (int g = 0; g < 4; g++) s[g] = fmaf(whh[g][j], hf[j], s[g]);
        }
      }
#pragma unroll
      for (int off = 32; off >= 1; off >>= 1) {
#pragma unroll
        for (int g = 0; g < 4; g++) s[g] += __shfl_xor(s[g], off, 64);
      }
      if (lane == 0) {
        float gi = s[0] + bs[0], gf = s[1] + bs[1];
        float gg = s[2] + bs[2], go = s[3] + bs[3];
        c_state = sigmf(gf) * c_state + sigmf(gi) * tanhf(gg);
        float h = sigmf(go) * tanhf(c_state);
        AGENT_ST64(&pk1[(long)(r - 1) * HID + unit], pack_h(h, r));
        h1_hist[(long)(r - 1) * HID + unit] = h;   // off-path, for out GEMM
      }
    }
  }
}

extern "C" void kernel_launch(void* const* d_in, const int* in_sizes, int n_in,
                              void* d_out, int out_size, void* d_ws, size_t ws_size,
                              hipStream_t stream) {
  const float* inputs = (const float*)d_in[0];
  const float* W_in  = (const float*)d_in[1];
  const float* b_in  = (const float*)d_in[2];
  const float* W_ih0 = (const float*)d_in[3];
  const float* W_hh0 = (const float*)d_in[4];
  const float* b_ih0 = (const float*)d_in[5];
  const float* b_hh0 = (const float*)d_in[6];
  const float* W_ih1 = (const float*)d_in[7];
  const float* W_hh1 = (const float*)d_in[8];
  const float* b_ih1 = (const float*)d_in[9];
  const float* b_hh1 = (const float*)d_in[10];
  const float* W_out = (const float*)d_in[11];
  const float* b_out = (const float*)d_in[12];
  float* out = (float*)d_out;

  char* ws = (char*)d_ws;
  float* pre_big = (float*)(ws);                          // [0,64) MB: pre0
  u64*   pk0     = (u64*)  (ws + ((size_t)64 << 20));     // [64,96) MB
  u64*   pk1     = (u64*)  (ws + ((size_t)96 << 20));     // [96,128) MB
  float* zbuf    = (float*)(ws + ((size_t)128 << 20));    // [128,144) MB: z, then h1
  float* xg      = (float*)(ws + ((size_t)144 << 20));    // 1 MB
  float* bsum0   = (float*)(ws + ((size_t)145 << 20));    // 16 KB
  float* b1sum   = (float*)(ws + ((size_t)145 << 20) + 16384);

  // 0) invalidate packet tags (64 MB zeros) + gather x + combine biases
  k_clear<<<2048, 256, 0, stream>>>(pk0, (long)2 * T_STEPS * HID);
  k_prep<<<1024, 256, 0, stream>>>(inputs, b_ih0, b_hh0, b_ih1, b_hh1,
                                   xg, bsum0, b1sum);
  // 1) z = x @ W_in^T + b_in            (4096 x 1024, K=64)
  gemm_nt<<<dim3(32, 8), 256, 0, stream>>>(xg, W_in, b_in, zbuf,
                                           T_STEPS, HID, 64, 0);
  // 2) pre0 = z @ W_ih0^T + (b_ih0+b_hh0)   (4096 x 4096, K=1024)
  gemm_nt<<<dim3(32, 32), 256, 0, stream>>>(zbuf, W_ih0, bsum0, pre_big,
                                            T_STEPS, 4096, HID, 0);
  // 3) fused pipelined 2-layer recurrence (z already consumed; h1 -> zbuf)
  lstm_fused<<<NBLK, THR, 0, stream>>>(pre_big, W_hh0, W_ih1, W_hh1, b1sum,
                                       pk0, pk1, zbuf);
  // 4) y = h1 @ W_out^T + b_out, scattered to (samples, steps, out)
  gemm_nt<<<dim3(32, 1), 256, 0, stream>>>(zbuf, W_out, b_out, out,
                                           T_STEPS, 64, HID, 1);
}

// Round 6
// 10815.620 us; speedup vs baseline: 1.5546x; 1.5546x over previous
//
#include <hip/hip_runtime.h>
#include <math.h>

// ---------------------------------------------------------------------------
// SimpleRNN (2-layer LSTM, H=1024, T=4096 sequential steps, batch=1 effective)
//
//   k_clear    : zero the packet buffers (tags must start invalid)
//   k_prep     : gather x (step-major), combine biases
//   gemm_nt    : C[M,N] = A[M,K] @ B[N,K]^T + bias
//   lstm_fused : ONE persistent 256-block kernel, both layer chains, layer-1
//                pipelined one step behind layer-0 (4097 round slots).
//                SYNC = DATA: h travels as 8-byte packets {float h, int tag}
//                via relaxed agent-scope 64-bit stores (one MALL trip/step).
//                R6: R4's 1024-thread conflict-free structure (stride-64 LDS
//                reads, 1 packet/thread poll) + weights held in VGPRs
//                (no 128KB/round LDS weight re-read) + fast sigmoid/tanh.
// ---------------------------------------------------------------------------

#define T_STEPS 4096
#define HID 1024
#define UPB 8            // hidden units per block
#define NBLK 256         // persistent blocks (128 per layer)

typedef unsigned long long u64;

#define AGENT_LD64(p) __hip_atomic_load((p), __ATOMIC_RELAXED, __HIP_MEMORY_SCOPE_AGENT)
#define AGENT_ST64(p, v) __hip_atomic_store((p), (v), __ATOMIC_RELAXED, __HIP_MEMORY_SCOPE_AGENT)

__device__ __forceinline__ u64 pack_h(float h, int tag) {
  return (u64)__float_as_uint(h) | ((u64)(unsigned)tag << 32);
}
__device__ __forceinline__ float pkt_val(u64 v) { return __uint_as_float((unsigned)v); }
__device__ __forceinline__ int pkt_tag(u64 v) { return (int)(v >> 32); }

__device__ __forceinline__ float fast_sigm(float x) {
  return __builtin_amdgcn_rcpf(1.f + __expf(-x));
}
__device__ __forceinline__ float fast_tanh(float x) {
  return 2.f * __builtin_amdgcn_rcpf(1.f + __expf(-2.f * x)) - 1.f;
}

__global__ void k_clear(u64* __restrict__ p, long n) {
  long i = (long)blockIdx.x * blockDim.x + threadIdx.x;
  long stride = (long)gridDim.x * blockDim.x;
  for (; i < n; i += stride) p[i] = 0ULL;
}

__global__ void k_prep(const float* __restrict__ inputs,
                       const float* __restrict__ b_ih0, const float* __restrict__ b_hh0,
                       const float* __restrict__ b_ih1, const float* __restrict__ b_hh1,
                       float* __restrict__ xg, float* __restrict__ bsum0,
                       float* __restrict__ b1sum) {
  int i = blockIdx.x * 256 + threadIdx.x;   // grid covers 262144
  if (i < T_STEPS * 64) {
    int t = i >> 6, d = i & 63;
    // x[t] = inputs[sample = t%32, step = t/32, :]
    xg[i] = inputs[(t & 31) * 8192 + (t >> 5) * 64 + d];
  }
  if (i < 4096) {
    bsum0[i] = b_ih0[i] + b_hh0[i];
    b1sum[i] = b_ih1[i] + b_hh1[i];
  }
}

// C = A @ B^T + bias.  A: M x K, B: N x K (both row-major, K contiguous).
// 128x128 tile, BK=8, 256 threads, 8x8 micro-tile per thread.
__global__ __launch_bounds__(256) void gemm_nt(
    const float* __restrict__ A, const float* __restrict__ B,
    const float* __restrict__ bias, float* __restrict__ C,
    int M, int N, int K, int mode) {
  __shared__ float As[8][128];
  __shared__ float Bs[8][128];
  const int tid = threadIdx.x;
  const int bm = blockIdx.x * 128;
  const int bn = blockIdx.y * 128;
  const int tm = tid >> 4;
  const int tn = tid & 15;
  const int lr = tid >> 1;
  const int lk = (tid & 1) * 4;

  float acc[8][8];
#pragma unroll
  for (int i = 0; i < 8; i++)
#pragma unroll
    for (int j = 0; j < 8; j++) acc[i][j] = 0.f;

  const float* Ap = A + (long)(bm + lr) * K + lk;
  const bool bvalid = (bn + lr) < N;
  const float* Bp = B + (long)(bvalid ? (bn + lr) : 0) * K + lk;

  for (int k0 = 0; k0 < K; k0 += 8) {
    float4 av = *(const float4*)(Ap + k0);
    float4 bv = bvalid ? *(const float4*)(Bp + k0) : make_float4(0.f, 0.f, 0.f, 0.f);
    As[lk + 0][lr] = av.x; As[lk + 1][lr] = av.y;
    As[lk + 2][lr] = av.z; As[lk + 3][lr] = av.w;
    Bs[lk + 0][lr] = bv.x; Bs[lk + 1][lr] = bv.y;
    Bs[lk + 2][lr] = bv.z; Bs[lk + 3][lr] = bv.w;
    __syncthreads();
#pragma unroll
    for (int kk = 0; kk < 8; kk++) {
      float a[8], b[8];
      *(float4*)&a[0] = *(const float4*)&As[kk][tm * 8];
      *(float4*)&a[4] = *(const float4*)&As[kk][tm * 8 + 4];
      *(float4*)&b[0] = *(const float4*)&Bs[kk][tn * 8];
      *(float4*)&b[4] = *(const float4*)&Bs[kk][tn * 8 + 4];
#pragma unroll
      for (int i = 0; i < 8; i++)
#pragma unroll
        for (int j = 0; j < 8; j++) acc[i][j] = fmaf(a[i], b[j], acc[i][j]);
    }
    __syncthreads();
  }

  const int n0 = bn + tn * 8;
  if (n0 < N) {
    float bb[8];
#pragma unroll
    for (int j = 0; j < 8; j++) bb[j] = bias[n0 + j];
#pragma unroll
    for (int i = 0; i < 8; i++) {
      int m = bm + tm * 8 + i;
      float4 v0, v1;
      v0.x = acc[i][0] + bb[0]; v0.y = acc[i][1] + bb[1];
      v0.z = acc[i][2] + bb[2]; v0.w = acc[i][3] + bb[3];
      v1.x = acc[i][4] + bb[4]; v1.y = acc[i][5] + bb[5];
      v1.z = acc[i][6] + bb[6]; v1.w = acc[i][7] + bb[7];
      if (mode == 0) {
        long o = (long)m * N + n0;
        *(float4*)&C[o] = v0; *(float4*)&C[o + 4] = v1;
      } else {
        long o = (long)(m & 31) * 8192 + (long)(m >> 5) * 64 + n0;
        *(float4*)&C[o] = v0; *(float4*)&C[o + 4] = v1;
      }
    }
  }
}

// Fused 2-layer recurrence. 256 blocks x 1024 threads; ~100 VGPR -> 16 waves/CU
// -> exactly 1 block/CU, all 256 co-resident.
// Wave w owns local rows 2w, 2w+1 (row rr = gate(rr>>3)*1024 + j0 + (rr&7));
// lane covers k = lane + 64*m (stride-64 LDS reads: conflict-free).
__global__ __launch_bounds__(1024, 1) void lstm_fused(
    const float* __restrict__ pre0,   // T x 4096 (layer-0 biases included)
    const float* __restrict__ Whh0,   // 4096 x 1024
    const float* __restrict__ Wih1,   // 4096 x 1024
    const float* __restrict__ Whh1,   // 4096 x 1024
    const float* __restrict__ b1sum,  // 4096
    u64* __restrict__ pk0,            // T x 1024 packets {h0, tag=t+1}
    u64* __restrict__ pk1,            // T x 1024 packets {h1, tag=t+1}
    float* __restrict__ h1_hist) {    // T x 1024 plain (for output GEMM)
  __shared__ float ha_lds[HID];       // 4 KB
  __shared__ float hb_lds[HID];       // 4 KB (layer-1 only)
  __shared__ float scr[32];
  __shared__ float pre_lds[32];
  const int b = blockIdx.x;
  const int tid = threadIdx.x;
  const int wave = tid >> 6;          // wave w owns local rows 2w, 2w+1
  const int lane = tid & 63;

  if (b < 128) {
    // ----------------------------- layer 0 -------------------------------
    const int j0 = b * UPB;
    // weight rows in VGPRs: w0[m] = Whh0[row(2w)][lane+64m], w1 likewise
    float w0[16], w1[16];
    {
      int r0 = 2 * wave, r1 = 2 * wave + 1;
      const float* s0 = Whh0 + (long)((r0 >> 3) * HID + j0 + (r0 & 7)) * HID + lane;
      const float* s1 = Whh0 + (long)((r1 >> 3) * HID + j0 + (r1 & 7)) * HID + lane;
#pragma unroll
      for (int m = 0; m < 16; m++) { w0[m] = s0[m << 6]; w1[m] = s1[m << 6]; }
    }
    float c_state = 0.f;              // valid in tid 0..7
    __syncthreads();

    for (int t = 0; t < T_STEPS; t++) {
      float preval = 0.f;             // prefetch overlaps the poll
      if (tid < 32)
        preval = pre0[(long)t * 4096 + ((tid >> 3) << 10) + j0 + (tid & 7)];

      if (t > 0) {
        const u64* p = pk0 + (long)(t - 1) * HID + tid;
        u64 v;
        for (;;) {
          v = AGENT_LD64(p);
          if (pkt_tag(v) == t) break;
          __builtin_amdgcn_s_sleep(1);
        }
        ha_lds[tid] = pkt_val(v);
      } else {
        ha_lds[tid] = 0.f;
      }
      if (tid < 32) pre_lds[tid] = preval;
      __syncthreads();

      float s0 = 0.f, s1 = 0.f;
#pragma unroll
      for (int m = 0; m < 16; m++) {
        float hv = ha_lds[lane + (m << 6)];
        s0 = fmaf(w0[m], hv, s0);
        s1 = fmaf(w1[m], hv, s1);
      }
#pragma unroll
      for (int off = 32; off >= 1; off >>= 1) {
        s0 += __shfl_xor(s0, off, 64);
        s1 += __shfl_xor(s1, off, 64);
      }
      if (lane == 0) { scr[wave * 2] = s0; scr[wave * 2 + 1] = s1; }
      __syncthreads();

      if (tid < UPB) {
        float gi = scr[tid]      + pre_lds[tid];
        float gf = scr[8 + tid]  + pre_lds[8 + tid];
        float gg = scr[16 + tid] + pre_lds[16 + tid];
        float go = scr[24 + tid] + pre_lds[24 + tid];
        c_state = fast_sigm(gf) * c_state + fast_sigm(gi) * fast_tanh(gg);
        float h = fast_sigm(go) * fast_tanh(c_state);
        // 8 consecutive u64 = one 64B line: coalesces into one write
        AGENT_ST64(&pk0[(long)t * HID + j0 + tid], pack_h(h, t + 1));
      }
    }
  } else {
    // ----------------------------- layer 1 -------------------------------
    const int j0 = (b - 128) * UPB;
    float wi0[16], wi1[16], wh0[16], wh1[16];
    {
      int r0 = 2 * wave, r1 = 2 * wave + 1;
      long o0 = (long)((r0 >> 3) * HID + j0 + (r0 & 7)) * HID + lane;
      long o1 = (long)((r1 >> 3) * HID + j0 + (r1 & 7)) * HID + lane;
      const float* a0 = Wih1 + o0; const float* a1 = Wih1 + o1;
      const float* c0 = Whh1 + o0; const float* c1 = Whh1 + o1;
#pragma unroll
      for (int m = 0; m < 16; m++) {
        wi0[m] = a0[m << 6]; wi1[m] = a1[m << 6];
        wh0[m] = c0[m << 6]; wh1[m] = c1[m << 6];
      }
    }
    if (tid < 32)
      pre_lds[tid] = b1sum[((tid >> 3) << 10) + j0 + (tid & 7)];  // constant
    float c_state = 0.f;              // valid in tid 0..7
    __syncthreads();

    for (int r = 1; r <= T_STEPS; r++) {   // computes h1[r-1]
      const u64* p0 = pk0 + (long)(r - 1) * HID + tid;
      const u64* p1 = pk1 + (long)((r >= 2) ? (r - 2) : 0) * HID + tid;
      u64 v0 = 0, v1 = 0;
      bool ok0 = false, ok1 = (r < 2);
      for (;;) {
        if (!ok0) { v0 = AGENT_LD64(p0); ok0 = (pkt_tag(v0) == r); }
        if (!ok1) { v1 = AGENT_LD64(p1); ok1 = (pkt_tag(v1) == r - 1); }
        if (ok0 && ok1) break;
        __builtin_amdgcn_s_sleep(1);
      }
      ha_lds[tid] = pkt_val(v0);
      hb_lds[tid] = (r >= 2) ? pkt_val(v1) : 0.f;
      __syncthreads();

      float s0 = 0.f, s1 = 0.f;
#pragma unroll
      for (int m = 0; m < 16; m++) {
        float av = ha_lds[lane + (m << 6)];
        float bv = hb_lds[lane + (m << 6)];
        s0 = fmaf(wi0[m], av, s0);
        s0 = fmaf(wh0[m], bv, s0);
        s1 = fmaf(wi1[m], av, s1);
        s1 = fmaf(wh1[m], bv, s1);
      }
#pragma unroll
      for (int off = 32; off >= 1; off >>= 1) {
        s0 += __shfl_xor(s0, off, 64);
        s1 += __shfl_xor(s1, off, 64);
      }
      if (lane == 0) { scr[wave * 2] = s0; scr[wave * 2 + 1] = s1; }
      __syncthreads();

      if (tid < UPB) {
        float gi = scr[tid]      + pre_lds[tid];
        float gf = scr[8 + tid]  + pre_lds[8 + tid];
        float gg = scr[16 + tid] + pre_lds[16 + tid];
        float go = scr[24 + tid] + pre_lds[24 + tid];
        c_state = fast_sigm(gf) * c_state + fast_sigm(gi) * fast_tanh(gg);
        float h = fast_sigm(go) * fast_tanh(c_state);
        AGENT_ST64(&pk1[(long)(r - 1) * HID + j0 + tid], pack_h(h, r));
        h1_hist[(long)(r - 1) * HID + j0 + tid] = h;   // off-path, for out GEMM
      }
    }
  }
}

extern "C" void kernel_launch(void* const* d_in, const int* in_sizes, int n_in,
                              void* d_out, int out_size, void* d_ws, size_t ws_size,
                              hipStream_t stream) {
  const float* inputs = (const float*)d_in[0];
  const float* W_in  = (const float*)d_in[1];
  const float* b_in  = (const float*)d_in[2];
  const float* W_ih0 = (const float*)d_in[3];
  const float* W_hh0 = (const float*)d_in[4];
  const float* b_ih0 = (const float*)d_in[5];
  const float* b_hh0 = (const float*)d_in[6];
  const float* W_ih1 = (const float*)d_in[7];
  const float* W_hh1 = (const float*)d_in[8];
  const float* b_ih1 = (const float*)d_in[9];
  const float* b_hh1 = (const float*)d_in[10];
  const float* W_out = (const float*)d_in[11];
  const float* b_out = (const float*)d_in[12];
  float* out = (float*)d_out;

  char* ws = (char*)d_ws;
  float* pre_big = (float*)(ws);                          // [0,64) MB: pre0
  u64*   pk0     = (u64*)  (ws + ((size_t)64 << 20));     // [64,96) MB
  u64*   pk1     = (u64*)  (ws + ((size_t)96 << 20));     // [96,128) MB
  float* zbuf    = (float*)(ws + ((size_t)128 << 20));    // [128,144) MB: z, then h1
  float* xg      = (float*)(ws + ((size_t)144 << 20));    // 1 MB
  float* bsum0   = (float*)(ws + ((size_t)145 << 20));    // 16 KB
  float* b1sum   = (float*)(ws + ((size_t)145 << 20) + 16384);

  // 0) invalidate packet tags (64 MB zeros) + gather x + combine biases
  k_clear<<<2048, 256, 0, stream>>>(pk0, (long)2 * T_STEPS * HID);
  k_prep<<<1024, 256, 0, stream>>>(inputs, b_ih0, b_hh0, b_ih1, b_hh1,
                                   xg, bsum0, b1sum);
  // 1) z = x @ W_in^T + b_in            (4096 x 1024, K=64)
  gemm_nt<<<dim3(32, 8), 256, 0, stream>>>(xg, W_in, b_in, zbuf,
                                           T_STEPS, HID, 64, 0);
  // 2) pre0 = z @ W_ih0^T + (b_ih0+b_hh0)   (4096 x 4096, K=1024)
  gemm_nt<<<dim3(32, 32), 256, 0, stream>>>(zbuf, W_ih0, bsum0, pre_big,
                                            T_STEPS, 4096, HID, 0);
  // 3) fused pipelined 2-layer recurrence (z already consumed; h1 -> zbuf)
  lstm_fused<<<NBLK, 1024, 0, stream>>>(pre_big, W_hh0, W_ih1, W_hh1, b1sum,
                                        pk0, pk1, zbuf);
  // 4) y = h1 @ W_out^T + b_out, scattered to (samples, steps, out)
  gemm_nt<<<dim3(32, 1), 256, 0, stream>>>(zbuf, W_out, b_out, out,
                                           T_STEPS, 64, HID, 1);
}